// Round 14
// baseline (351.243 us; speedup 1.0000x reference)
//
#include <hip/hip_runtime.h>

// MultiHeadSelfAttention2D: B=8, C=128, H=W=64, N=4096, heads=4, hd=32
// Pipeline: wprep (weights f32 -> bf16; Wq pre-scaled by 1/sqrt(32)*log2(e))
//           qkv  (FUSED: x-tile -> LDS transpose/bf16 -> Q,K,V for 64 tokens;
//                 V written PRE-FRAGMENTED per kv-block)
//           attn (flash attention, 64 q-rows/wave, 4-way split-KV, MAX-FREE
//                 softmax, native __bf16 pack, XCD swizzle, LDS merge;
//                 launch_bounds(256,6) + 26112B LDS -> 6 waves/SIMD resident)
//           projo (output projection, transposed store)

using f32x4  = __attribute__((ext_vector_type(4))) float;
using bf16x8 = __attribute__((ext_vector_type(8))) short;   // MFMA operand (4 VGPRs)
using bfv8   = __attribute__((ext_vector_type(8))) __bf16;  // native bf16 vector

#define QSCALE 0.17677669529663687f  // 1/sqrt(32)
#define LOG2E  1.4426950408889634f
#define QKS    (QSCALE * LOG2E)      // folded into Wq/bq -> S = logit*log2e

static __device__ __forceinline__ unsigned short f2bf(float f) {
    union { float f; unsigned int u; } v; v.f = f;
    unsigned int r = v.u + 0x7FFFu + ((v.u >> 16) & 1u);  // RNE
    return (unsigned short)(r >> 16);
}

static __device__ __forceinline__ f32x4 mfma16(bf16x8 a, bf16x8 b, f32x4 c) {
    return __builtin_amdgcn_mfma_f32_16x16x32_bf16(a, b, c, 0, 0, 0);
}

// ---------------------------------------------------------------------------
// wprep: weights f32 -> bf16 (4 blocks, one per matrix)
__global__ __launch_bounds__(256) void k_wprep(
    const float* __restrict__ Wq, const float* __restrict__ Wk,
    const float* __restrict__ Wv, const float* __restrict__ Wo,
    unsigned short* __restrict__ Wb)
{
    const int m = blockIdx.x;
    const float* W = (m == 0) ? Wq : (m == 1) ? Wk : (m == 2) ? Wv : Wo;
    const float s = (m == 0) ? QKS : 1.0f;
    for (int idx = threadIdx.x; idx < 16384; idx += 256)
        Wb[m * 16384 + idx] = f2bf(W[idx] * s);
}

// ---------------------------------------------------------------------------
// qkv (FUSED prep+proj3): grid 512, each block = 64 tokens (one b, n0..n0+63).
// Phase 1: load x[b][c][n0..+63] f32, convert bf16, LDS-transpose to
//          tl[token][c]. Phase 2: per wave (16 tokens), mat=0..2 MFMA GEMM.
// Q,K stored (bh, n, 32) bf16 (Q pre-scaled by QKS).
// V stored per kv-block as a 2KB tile [32 d][32 kv] with row pre-fragmented:
// position 8*g + 4*hi + lo <-> kv = 16*hi + 4*g + lo (attn B-frag = one 16B load).
__global__ __launch_bounds__(256) void k_qkv(
    const float* __restrict__ x, const unsigned short* __restrict__ Wb,
    const float* __restrict__ bq, const float* __restrict__ bk, const float* __restrict__ bv,
    unsigned short* __restrict__ Qb, unsigned short* __restrict__ Kb,
    unsigned short* __restrict__ Vt)
{
    __shared__ unsigned short tl[64][136];  // [token j][c], 272B row stride
    const int tid = threadIdx.x;
    const int gt0 = blockIdx.x * 64;
    const int b = gt0 >> 12, n0 = gt0 & 4095;

    const float* xb = x + (size_t)b * 128 * 4096 + n0;
    #pragma unroll
    for (int k = 0; k < 8; ++k) {
        const int flat = k * 1024 + tid * 4;   // 8192 floats = 128c x 64n
        const int c = flat >> 6, j = flat & 63;
        const float4 v = *(const float4*)(xb + (size_t)c * 4096 + j);
        tl[j + 0][c] = f2bf(v.x);
        tl[j + 1][c] = f2bf(v.y);
        tl[j + 2][c] = f2bf(v.z);
        tl[j + 3][c] = f2bf(v.w);
    }
    __syncthreads();

    const int widx = tid >> 6;
    const int lane = tid & 63, g = lane >> 4, l15 = lane & 15;
    const int row0 = gt0 + widx * 16;
    const int gt_row = row0 + l15;

    bf16x8 tf[4];
    #pragma unroll
    for (int kc = 0; kc < 4; ++kc)
        tf[kc] = *(const bf16x8*)&tl[widx * 16 + l15][kc * 32 + g * 8];

    for (int mat = 0; mat < 3; ++mat) {
        const unsigned short* Wm = Wb + mat * 16384;
        const float* bias = (mat == 0) ? bq : (mat == 1) ? bk : bv;

        #pragma unroll
        for (int ot = 0; ot < 8; ++ot) {
            f32x4 acc;
            if (mat < 2) {
                float bb = bias[ot * 16 + l15];
                if (mat == 0) bb *= QKS;
                acc[0] = bb; acc[1] = bb; acc[2] = bb; acc[3] = bb;
            } else {
                #pragma unroll
                for (int r = 0; r < 4; ++r) acc[r] = bias[ot * 16 + 4 * g + r];
            }
            #pragma unroll
            for (int kc = 0; kc < 4; ++kc) {
                bf16x8 wf = *(const bf16x8*)(Wm + (size_t)(ot * 16 + l15) * 128 + kc * 32 + g * 8);
                acc = (mat == 2) ? mfma16(wf, tf[kc], acc) : mfma16(tf[kc], wf, acc);
            }
            if (mat < 2) {
                unsigned short* dst = (mat == 0) ? Qb : Kb;
                const int o = ot * 16 + l15, h = o >> 5, d = o & 31;
                #pragma unroll
                for (int r = 0; r < 4; ++r) {
                    const int gt = row0 + 4 * g + r;
                    const int bb2 = gt >> 12, n = gt & 4095;
                    dst[(((size_t)(bb2 * 4 + h)) * 4096 + n) * 32 + d] = f2bf(acc[r]);
                }
            } else {
                const int n = gt_row & 4095;
                const int n31 = n & 31;
                const int pos = ((n31 >> 2) & 3) * 8 + ((n31 >> 4) & 1) * 4 + (n31 & 3);
                #pragma unroll
                for (int r = 0; r < 4; ++r) {
                    const int o = ot * 16 + 4 * g + r, h2 = o >> 5, d = o & 31;
                    const size_t tb2 = ((size_t)(b * 4 + h2) * 128 + ((n >> 5) & 127)) * 1024;
                    Vt[tb2 + d * 32 + pos] = f2bf(acc[r]);
                }
            }
        }
    }
}

// ---------------------------------------------------------------------------
// attn: flash attention, 4-way split-KV, MAX-FREE. Block = 4 waves = 1 q-tile
// (64 rows) x 4 KV quarters. Wave widx: KV in [widx*1024, widx*1024+1024).
// Each wave holds 4 Q-frags -> one K/V load feeds 8 QK + 12 PV MFMAs.
// Swapped QK^T: mfma(K,Q) -> lane(g,l15) reg r = S[q=f*16+l15][kv0(+16)+4g+r];
// S is already logit*log2e -> p = exp2(S) directly (max-free).
// P packed via native __bf16 casts (asm pack = R7/R9 miscompile).
// V B-frag is ONE 16B load (pre-fragmented Vt, same slot map as P).
// Denominator = extra PV MFMA against constant-1.0 B operand.
// Quarters merged through LDS by plain addition, wave 0 writes.
// launch_bounds(256,6): VGPR cap 85 (was 88) + LDS 26112B (pad 66 not 68)
// -> 6 waves/SIMD resident (was 5). 2-bank stride at merge = free (m136).
__global__ __launch_bounds__(256, 6) void k_attn(
    const unsigned short* __restrict__ Qb, const unsigned short* __restrict__ Kb,
    const unsigned short* __restrict__ Vt, unsigned short* __restrict__ Ob)
{
    const int bid = blockIdx.x;
    const int swz = (bid & 7) * 256 + (bid >> 3);
    const int widx = threadIdx.x >> 6;           // KV quarter 0..3
    const int bh = swz >> 6, q0 = (swz & 63) * 64;
    const int lane = threadIdx.x & 63, g = lane >> 4, l15 = lane & 15;

    __shared__ float lacc[3][32][66];   // [writer][col d][row q], pad 66 (2-bank)
    __shared__ float lden[3][64];       // [writer][row q]

    bf16x8 qf[4];
    #pragma unroll
    for (int f = 0; f < 4; ++f)
        qf[f] = *(const bf16x8*)(Qb + ((size_t)bh * 4096 + q0 + f * 16 + l15) * 32 + g * 8);

    const unsigned short* kp = Kb + (size_t)bh * 131072
                             + (size_t)(widx * 1024 + l15) * 32 + g * 8;
    const unsigned short* vp = Vt + (size_t)bh * 131072 + (size_t)widx * 32768
                             + l15 * 32 + g * 8;

    bf16x8 onesf;
    #pragma unroll
    for (int j = 0; j < 8; ++j) onesf[j] = (short)0x3F80;  // bf16 1.0

    f32x4 aO[4][2];
    f32x4 aD[4];
    #pragma unroll
    for (int f = 0; f < 4; ++f) {
        aO[f][0] = f32x4{0.f,0.f,0.f,0.f};
        aO[f][1] = f32x4{0.f,0.f,0.f,0.f};
        aD[f]    = f32x4{0.f,0.f,0.f,0.f};
    }
    const f32x4 z = {0.f,0.f,0.f,0.f};

    for (int it = 0; it < 32; ++it) {
        const bf16x8 kf0 = *(const bf16x8*)(kp);
        const bf16x8 kf1 = *(const bf16x8*)(kp + 512);   // rows +16
        const bf16x8 vf0 = *(const bf16x8*)(vp);         // d = l15
        const bf16x8 vf1 = *(const bf16x8*)(vp + 512);   // d = 16 + l15
        kp += 1024;
        vp += 1024;

        #pragma unroll
        for (int f = 0; f < 4; ++f) {
            const f32x4 s0 = mfma16(kf0, qf[f], z);
            const f32x4 s1 = mfma16(kf1, qf[f], z);
            bfv8 pb;
            #pragma unroll
            for (int i = 0; i < 4; ++i) {
                pb[i]     = (__bf16)__builtin_amdgcn_exp2f(s0[i]);
                pb[4 + i] = (__bf16)__builtin_amdgcn_exp2f(s1[i]);
            }
            const bf16x8 pa = __builtin_bit_cast(bf16x8, pb);
            aO[f][0] = mfma16(pa, vf0, aO[f][0]);
            aO[f][1] = mfma16(pa, vf1, aO[f][1]);
            aD[f]    = mfma16(pa, onesf, aD[f]);
        }
    }

    if (widx != 0) {
        const int s = widx - 1;
        #pragma unroll
        for (int f = 0; f < 4; ++f) {
            *(f32x4*)&lacc[s][l15][f * 16 + 4 * g]      = aO[f][0];
            *(f32x4*)&lacc[s][16 + l15][f * 16 + 4 * g] = aO[f][1];
            if (l15 == 0) {
                #pragma unroll
                for (int r = 0; r < 4; ++r)
                    lden[s][f * 16 + 4 * g + r] = aD[f][r];
            }
        }
    }
    __syncthreads();
    if (widx != 0) return;

    const int b = bh >> 2, h = bh & 3;
    #pragma unroll
    for (int f = 0; f < 4; ++f) {
        #pragma unroll
        for (int r = 0; r < 4; ++r) {
            const int row = f * 16 + 4 * g + r;
            const float rd = 1.0f / (aD[f][r] + lden[0][row] + lden[1][row] + lden[2][row]);
            const float o0 = aO[f][0][r] + lacc[0][l15][row]
                           + lacc[1][l15][row] + lacc[2][l15][row];
            const float o1 = aO[f][1][r] + lacc[0][16 + l15][row]
                           + lacc[1][16 + l15][row] + lacc[2][16 + l15][row];
            const size_t base = ((size_t)b * 4096 + q0 + row) * 128 + h * 32;
            Ob[base + l15]      = f2bf(o0 * rd);
            Ob[base + 16 + l15] = f2bf(o1 * rd);
        }
    }
}

// ---------------------------------------------------------------------------
// projo: out(b,c,n) = (O @ Wo^T + bo)^T via swapped MFMA (A=Wo rows, B=O rows)
__global__ __launch_bounds__(256) void k_projo(
    const unsigned short* __restrict__ Ob, const unsigned short* __restrict__ Wob,
    const float* __restrict__ bo, float* __restrict__ out)
{
    const int widx = threadIdx.x >> 6;
    const int lane = threadIdx.x & 63, g = lane >> 4, l15 = lane & 15;
    const int gt = blockIdx.x * 64 + widx * 16 + l15;  // token (col of D)
    const int b = gt >> 12, n = gt & 4095;

    bf16x8 of[4];
    #pragma unroll
    for (int kc = 0; kc < 4; ++kc)
        of[kc] = *(const bf16x8*)(Ob + (size_t)gt * 128 + kc * 32 + g * 8);

    #pragma unroll
    for (int ot = 0; ot < 8; ++ot) {
        f32x4 acc;
        #pragma unroll
        for (int r = 0; r < 4; ++r) acc[r] = bo[ot * 16 + 4 * g + r];
        #pragma unroll
        for (int kc = 0; kc < 4; ++kc) {
            bf16x8 wf = *(const bf16x8*)(Wob + (size_t)(ot * 16 + l15) * 128 + kc * 32 + g * 8);
            acc = mfma16(wf, of[kc], acc);
        }
        #pragma unroll
        for (int r = 0; r < 4; ++r)
            out[((size_t)b * 128 + ot * 16 + 4 * g + r) * 4096 + n] = acc[r];
    }
}

// ---------------------------------------------------------------------------
extern "C" void kernel_launch(void* const* d_in, const int* in_sizes, int n_in,
                              void* d_out, int out_size, void* d_ws, size_t ws_size,
                              hipStream_t stream)
{
    const float* x  = (const float*)d_in[0];
    const float* Wq = (const float*)d_in[1];
    const float* bq = (const float*)d_in[2];
    const float* Wk = (const float*)d_in[3];
    const float* bk = (const float*)d_in[4];
    const float* Wv = (const float*)d_in[5];
    const float* bv = (const float*)d_in[6];
    const float* Wo = (const float*)d_in[7];
    const float* bo = (const float*)d_in[8];
    float* out = (float*)d_out;

    char* ws = (char*)d_ws;
    unsigned short* Wb   = (unsigned short*)(ws +  8388608);  //    131,072 B
    unsigned short* Qb   = (unsigned short*)(ws +  8519680);  //  8,388,608 B
    unsigned short* Kb   = (unsigned short*)(ws + 16908288);  //  8,388,608 B
    unsigned short* Vt   = (unsigned short*)(ws + 25296896);  //  8,388,608 B
    unsigned short* Ob   = (unsigned short*)(ws + 33685504);  //  8,388,608 B -> 42.1 MB total

    k_wprep<<<dim3(4),    dim3(256), 0, stream>>>(Wq, Wk, Wv, Wo, Wb);
    k_qkv  <<<dim3(512),  dim3(256), 0, stream>>>(x, Wb, bq, bk, bv, Qb, Kb, Vt);
    k_attn <<<dim3(2048), dim3(256), 0, stream>>>(Qb, Kb, Vt, Ob);
    k_projo<<<dim3(512),  dim3(256), 0, stream>>>(Ob, Wb + 3 * 16384, bo, out);
}

// Round 15
// 173.769 us; speedup vs baseline: 2.0213x; 2.0213x over previous
//
#include <hip/hip_runtime.h>

// MultiHeadSelfAttention2D: B=8, C=128, H=W=64, N=4096, heads=4, hd=32
// Pipeline: wprep (weights f32 -> bf16; Wq pre-scaled by 1/sqrt(32)*log2(e))
//           qkv  (FUSED: x-tile -> LDS transpose/bf16 -> Q,K,V for 64 tokens;
//                 V written PRE-FRAGMENTED per kv-block)
//           attn (flash attention, 64 q-rows/wave, 4-way split-KV, MAX-FREE
//                 softmax, native __bf16 pack, XCD swizzle, LDS merge)
//           projo (output projection, transposed store)
// NOTE (R14 lesson): do NOT set a min-waves launch-bounds arg on k_attn.
// The 48-f32 accumulator state needs ~88 VGPRs; capping to 85 (256,6) made
// the allocator spill accumulators to scratch (FETCH 12->369 MB, 2.4x slower).
// 5 waves/SIMD at VGPR=88 is the correct operating point for this structure.

using f32x4  = __attribute__((ext_vector_type(4))) float;
using bf16x8 = __attribute__((ext_vector_type(8))) short;   // MFMA operand (4 VGPRs)
using bfv8   = __attribute__((ext_vector_type(8))) __bf16;  // native bf16 vector

#define QSCALE 0.17677669529663687f  // 1/sqrt(32)
#define LOG2E  1.4426950408889634f
#define QKS    (QSCALE * LOG2E)      // folded into Wq/bq -> S = logit*log2e

static __device__ __forceinline__ unsigned short f2bf(float f) {
    union { float f; unsigned int u; } v; v.f = f;
    unsigned int r = v.u + 0x7FFFu + ((v.u >> 16) & 1u);  // RNE
    return (unsigned short)(r >> 16);
}

static __device__ __forceinline__ f32x4 mfma16(bf16x8 a, bf16x8 b, f32x4 c) {
    return __builtin_amdgcn_mfma_f32_16x16x32_bf16(a, b, c, 0, 0, 0);
}

// ---------------------------------------------------------------------------
// wprep: weights f32 -> bf16 (4 blocks, one per matrix)
__global__ __launch_bounds__(256) void k_wprep(
    const float* __restrict__ Wq, const float* __restrict__ Wk,
    const float* __restrict__ Wv, const float* __restrict__ Wo,
    unsigned short* __restrict__ Wb)
{
    const int m = blockIdx.x;
    const float* W = (m == 0) ? Wq : (m == 1) ? Wk : (m == 2) ? Wv : Wo;
    const float s = (m == 0) ? QKS : 1.0f;
    for (int idx = threadIdx.x; idx < 16384; idx += 256)
        Wb[m * 16384 + idx] = f2bf(W[idx] * s);
}

// ---------------------------------------------------------------------------
// qkv (FUSED prep+proj3): grid 512, each block = 64 tokens (one b, n0..n0+63).
// Phase 1: load x[b][c][n0..+63] f32, convert bf16, LDS-transpose to
//          tl[token][c]. Phase 2: per wave (16 tokens), mat=0..2 MFMA GEMM.
// Q,K stored (bh, n, 32) bf16 (Q pre-scaled by QKS).
// V stored per kv-block as a 2KB tile [32 d][32 kv] with row pre-fragmented:
// position 8*g + 4*hi + lo <-> kv = 16*hi + 4*g + lo (attn B-frag = one 16B load).
__global__ __launch_bounds__(256) void k_qkv(
    const float* __restrict__ x, const unsigned short* __restrict__ Wb,
    const float* __restrict__ bq, const float* __restrict__ bk, const float* __restrict__ bv,
    unsigned short* __restrict__ Qb, unsigned short* __restrict__ Kb,
    unsigned short* __restrict__ Vt)
{
    __shared__ unsigned short tl[64][136];  // [token j][c], 272B row stride
    const int tid = threadIdx.x;
    const int gt0 = blockIdx.x * 64;
    const int b = gt0 >> 12, n0 = gt0 & 4095;

    const float* xb = x + (size_t)b * 128 * 4096 + n0;
    #pragma unroll
    for (int k = 0; k < 8; ++k) {
        const int flat = k * 1024 + tid * 4;   // 8192 floats = 128c x 64n
        const int c = flat >> 6, j = flat & 63;
        const float4 v = *(const float4*)(xb + (size_t)c * 4096 + j);
        tl[j + 0][c] = f2bf(v.x);
        tl[j + 1][c] = f2bf(v.y);
        tl[j + 2][c] = f2bf(v.z);
        tl[j + 3][c] = f2bf(v.w);
    }
    __syncthreads();

    const int widx = tid >> 6;
    const int lane = tid & 63, g = lane >> 4, l15 = lane & 15;
    const int row0 = gt0 + widx * 16;
    const int gt_row = row0 + l15;

    bf16x8 tf[4];
    #pragma unroll
    for (int kc = 0; kc < 4; ++kc)
        tf[kc] = *(const bf16x8*)&tl[widx * 16 + l15][kc * 32 + g * 8];

    for (int mat = 0; mat < 3; ++mat) {
        const unsigned short* Wm = Wb + mat * 16384;
        const float* bias = (mat == 0) ? bq : (mat == 1) ? bk : bv;

        #pragma unroll
        for (int ot = 0; ot < 8; ++ot) {
            f32x4 acc;
            if (mat < 2) {
                float bb = bias[ot * 16 + l15];
                if (mat == 0) bb *= QKS;
                acc[0] = bb; acc[1] = bb; acc[2] = bb; acc[3] = bb;
            } else {
                #pragma unroll
                for (int r = 0; r < 4; ++r) acc[r] = bias[ot * 16 + 4 * g + r];
            }
            #pragma unroll
            for (int kc = 0; kc < 4; ++kc) {
                bf16x8 wf = *(const bf16x8*)(Wm + (size_t)(ot * 16 + l15) * 128 + kc * 32 + g * 8);
                acc = (mat == 2) ? mfma16(wf, tf[kc], acc) : mfma16(tf[kc], wf, acc);
            }
            if (mat < 2) {
                unsigned short* dst = (mat == 0) ? Qb : Kb;
                const int o = ot * 16 + l15, h = o >> 5, d = o & 31;
                #pragma unroll
                for (int r = 0; r < 4; ++r) {
                    const int gt = row0 + 4 * g + r;
                    const int bb2 = gt >> 12, n = gt & 4095;
                    dst[(((size_t)(bb2 * 4 + h)) * 4096 + n) * 32 + d] = f2bf(acc[r]);
                }
            } else {
                const int n = gt_row & 4095;
                const int n31 = n & 31;
                const int pos = ((n31 >> 2) & 3) * 8 + ((n31 >> 4) & 1) * 4 + (n31 & 3);
                #pragma unroll
                for (int r = 0; r < 4; ++r) {
                    const int o = ot * 16 + 4 * g + r, h2 = o >> 5, d = o & 31;
                    const size_t tb2 = ((size_t)(b * 4 + h2) * 128 + ((n >> 5) & 127)) * 1024;
                    Vt[tb2 + d * 32 + pos] = f2bf(acc[r]);
                }
            }
        }
    }
}

// ---------------------------------------------------------------------------
// attn: flash attention, 4-way split-KV, MAX-FREE. Block = 4 waves = 1 q-tile
// (64 rows) x 4 KV quarters. Wave widx: KV in [widx*1024, widx*1024+1024).
// Each wave holds 4 Q-frags -> one K/V load feeds 8 QK + 12 PV MFMAs.
// Swapped QK^T: mfma(K,Q) -> lane(g,l15) reg r = S[q=f*16+l15][kv0(+16)+4g+r];
// S is already logit*log2e -> p = exp2(S) directly (max-free).
// P packed via native __bf16 casts (asm pack = R7/R9 miscompile).
// V B-frag is ONE 16B load (pre-fragmented Vt, same slot map as P).
// Denominator = extra PV MFMA against constant-1.0 B operand.
// Quarters merged through LDS by plain addition, wave 0 writes.
__global__ __launch_bounds__(256) void k_attn(
    const unsigned short* __restrict__ Qb, const unsigned short* __restrict__ Kb,
    const unsigned short* __restrict__ Vt, unsigned short* __restrict__ Ob)
{
    const int bid = blockIdx.x;
    const int swz = (bid & 7) * 256 + (bid >> 3);
    const int widx = threadIdx.x >> 6;           // KV quarter 0..3
    const int bh = swz >> 6, q0 = (swz & 63) * 64;
    const int lane = threadIdx.x & 63, g = lane >> 4, l15 = lane & 15;

    __shared__ float lacc[3][32][68];   // [writer][col d][row q], padded
    __shared__ float lden[3][64];       // [writer][row q]

    bf16x8 qf[4];
    #pragma unroll
    for (int f = 0; f < 4; ++f)
        qf[f] = *(const bf16x8*)(Qb + ((size_t)bh * 4096 + q0 + f * 16 + l15) * 32 + g * 8);

    const unsigned short* kp = Kb + (size_t)bh * 131072
                             + (size_t)(widx * 1024 + l15) * 32 + g * 8;
    const unsigned short* vp = Vt + (size_t)bh * 131072 + (size_t)widx * 32768
                             + l15 * 32 + g * 8;

    bf16x8 onesf;
    #pragma unroll
    for (int j = 0; j < 8; ++j) onesf[j] = (short)0x3F80;  // bf16 1.0

    f32x4 aO[4][2];
    f32x4 aD[4];
    #pragma unroll
    for (int f = 0; f < 4; ++f) {
        aO[f][0] = f32x4{0.f,0.f,0.f,0.f};
        aO[f][1] = f32x4{0.f,0.f,0.f,0.f};
        aD[f]    = f32x4{0.f,0.f,0.f,0.f};
    }
    const f32x4 z = {0.f,0.f,0.f,0.f};

    for (int it = 0; it < 32; ++it) {
        const bf16x8 kf0 = *(const bf16x8*)(kp);
        const bf16x8 kf1 = *(const bf16x8*)(kp + 512);   // rows +16
        const bf16x8 vf0 = *(const bf16x8*)(vp);         // d = l15
        const bf16x8 vf1 = *(const bf16x8*)(vp + 512);   // d = 16 + l15
        kp += 1024;
        vp += 1024;

        #pragma unroll
        for (int f = 0; f < 4; ++f) {
            const f32x4 s0 = mfma16(kf0, qf[f], z);
            const f32x4 s1 = mfma16(kf1, qf[f], z);
            bfv8 pb;
            #pragma unroll
            for (int i = 0; i < 4; ++i) {
                pb[i]     = (__bf16)__builtin_amdgcn_exp2f(s0[i]);
                pb[4 + i] = (__bf16)__builtin_amdgcn_exp2f(s1[i]);
            }
            const bf16x8 pa = __builtin_bit_cast(bf16x8, pb);
            aO[f][0] = mfma16(pa, vf0, aO[f][0]);
            aO[f][1] = mfma16(pa, vf1, aO[f][1]);
            aD[f]    = mfma16(pa, onesf, aD[f]);
        }
    }

    if (widx != 0) {
        const int s = widx - 1;
        #pragma unroll
        for (int f = 0; f < 4; ++f) {
            *(f32x4*)&lacc[s][l15][f * 16 + 4 * g]      = aO[f][0];
            *(f32x4*)&lacc[s][16 + l15][f * 16 + 4 * g] = aO[f][1];
            if (l15 == 0) {
                #pragma unroll
                for (int r = 0; r < 4; ++r)
                    lden[s][f * 16 + 4 * g + r] = aD[f][r];
            }
        }
    }
    __syncthreads();
    if (widx != 0) return;

    const int b = bh >> 2, h = bh & 3;
    #pragma unroll
    for (int f = 0; f < 4; ++f) {
        #pragma unroll
        for (int r = 0; r < 4; ++r) {
            const int row = f * 16 + 4 * g + r;
            const float rd = 1.0f / (aD[f][r] + lden[0][row] + lden[1][row] + lden[2][row]);
            const float o0 = aO[f][0][r] + lacc[0][l15][row]
                           + lacc[1][l15][row] + lacc[2][l15][row];
            const float o1 = aO[f][1][r] + lacc[0][16 + l15][row]
                           + lacc[1][16 + l15][row] + lacc[2][16 + l15][row];
            const size_t base = ((size_t)b * 4096 + q0 + row) * 128 + h * 32;
            Ob[base + l15]      = f2bf(o0 * rd);
            Ob[base + 16 + l15] = f2bf(o1 * rd);
        }
    }
}

// ---------------------------------------------------------------------------
// projo: out(b,c,n) = (O @ Wo^T + bo)^T via swapped MFMA (A=Wo rows, B=O rows)
__global__ __launch_bounds__(256) void k_projo(
    const unsigned short* __restrict__ Ob, const unsigned short* __restrict__ Wob,
    const float* __restrict__ bo, float* __restrict__ out)
{
    const int widx = threadIdx.x >> 6;
    const int lane = threadIdx.x & 63, g = lane >> 4, l15 = lane & 15;
    const int gt = blockIdx.x * 64 + widx * 16 + l15;  // token (col of D)
    const int b = gt >> 12, n = gt & 4095;

    bf16x8 of[4];
    #pragma unroll
    for (int kc = 0; kc < 4; ++kc)
        of[kc] = *(const bf16x8*)(Ob + (size_t)gt * 128 + kc * 32 + g * 8);

    #pragma unroll
    for (int ot = 0; ot < 8; ++ot) {
        f32x4 acc;
        #pragma unroll
        for (int r = 0; r < 4; ++r) acc[r] = bo[ot * 16 + 4 * g + r];
        #pragma unroll
        for (int kc = 0; kc < 4; ++kc) {
            bf16x8 wf = *(const bf16x8*)(Wob + (size_t)(ot * 16 + l15) * 128 + kc * 32 + g * 8);
            acc = mfma16(wf, of[kc], acc);
        }
        #pragma unroll
        for (int r = 0; r < 4; ++r)
            out[((size_t)b * 128 + ot * 16 + 4 * g + r) * 4096 + n] = acc[r];
    }
}

// ---------------------------------------------------------------------------
extern "C" void kernel_launch(void* const* d_in, const int* in_sizes, int n_in,
                              void* d_out, int out_size, void* d_ws, size_t ws_size,
                              hipStream_t stream)
{
    const float* x  = (const float*)d_in[0];
    const float* Wq = (const float*)d_in[1];
    const float* bq = (const float*)d_in[2];
    const float* Wk = (const float*)d_in[3];
    const float* bk = (const float*)d_in[4];
    const float* Wv = (const float*)d_in[5];
    const float* bv = (const float*)d_in[6];
    const float* Wo = (const float*)d_in[7];
    const float* bo = (const float*)d_in[8];
    float* out = (float*)d_out;

    char* ws = (char*)d_ws;
    unsigned short* Wb   = (unsigned short*)(ws +  8388608);  //    131,072 B
    unsigned short* Qb   = (unsigned short*)(ws +  8519680);  //  8,388,608 B
    unsigned short* Kb   = (unsigned short*)(ws + 16908288);  //  8,388,608 B
    unsigned short* Vt   = (unsigned short*)(ws + 25296896);  //  8,388,608 B
    unsigned short* Ob   = (unsigned short*)(ws + 33685504);  //  8,388,608 B -> 42.1 MB total

    k_wprep<<<dim3(4),    dim3(256), 0, stream>>>(Wq, Wk, Wv, Wo, Wb);
    k_qkv  <<<dim3(512),  dim3(256), 0, stream>>>(x, Wb, bq, bk, bv, Qb, Kb, Vt);
    k_attn <<<dim3(2048), dim3(256), 0, stream>>>(Qb, Kb, Vt, Ob);
    k_projo<<<dim3(512),  dim3(256), 0, stream>>>(Ob, Wb + 3 * 16384, bo, out);
}